// Round 4
// baseline (856.574 us; speedup 1.0000x reference)
//
#include <hip/hip_runtime.h>
#include <cmath>

#define NN 50000
#define CAP 64               // ELL capacity; P(deg > 64 anywhere) ~ 1e-16 for E=800k

constexpr int NR   = 50016;     // rows per panel: NN + sentinel row (50000) + pad
constexpr int PSTR = NR * 32;   // ushorts per 32-feature panel (~3.2 MB)

typedef short v8s __attribute__((ext_vector_type(8)));   // 8 x bf16 (4 VGPRs)
typedef float v4f __attribute__((ext_vector_type(4)));

__device__ __forceinline__ float b2f(unsigned short u) {
    return __uint_as_float(((unsigned int)u) << 16);
}
__device__ __forceinline__ unsigned short f2b(float f) {
    unsigned int x = __float_as_uint(f);
    x += 0x7fffu + ((x >> 16) & 1u);          // round-to-nearest-even
    return (unsigned short)(x >> 16);
}

// async global->LDS, 16B per lane. LDS dest must be wave-contiguous (base + lane*16).
__device__ __forceinline__ void gld16(const void* g, void* l) {
    __builtin_amdgcn_global_load_lds(
        (const __attribute__((address_space(1))) unsigned int*)g,
        (__attribute__((address_space(3))) unsigned int*)l, 16, 0, 0);
}

// ---- dtype sniffer: mode=0 -> inputs are bf16, mode=1 -> inputs are float32 ----
__global__ void sniff_kernel(const unsigned short* __restrict__ x, int* __restrict__ mode) {
    if (threadIdx.x == 0 && blockIdx.x == 0) {
        int c = 0;
        for (int i = 0; i < 128; ++i) {
            unsigned int e = (x[i] >> 7) & 0xFFu;
            if (e >= 100u && e <= 140u) ++c;
        }
        *mode = (c >= 112) ? 0 : 1;
    }
}

// ---- ELL fill: one atomic pass, no scan ----
__global__ void fill_kernel(const int* __restrict__ src, const int* __restrict__ dst,
                            int* __restrict__ cnt, unsigned short* __restrict__ ell, int E) {
    int e = blockIdx.x * blockDim.x + threadIdx.x;
    if (e < E) {
        int d = dst[e];
        int pos = atomicAdd(&cnt[d], 1);
        if (pos < CAP) ell[d * CAP + pos] = (unsigned short)src[e];
    }
}

// ---- pad empty ELL slots with sentinel row NN (dinv[NN]=0, panel row NN zeroed) ----
__global__ void pad_kernel(const int* __restrict__ cnt, unsigned short* __restrict__ ell) {
    int node = blockIdx.x * 4 + (threadIdx.x >> 6);
    int lane = threadIdx.x & 63;
    if (node < NN) {
        int c = cnt[node];
        if (lane >= c) ell[node * CAP + lane] = (unsigned short)NN;
    }
}

// ---- dinv from counts (n = NN+1: sentinel entry = 0) ----
__global__ void dinv_kernel(const int* __restrict__ cnt, float* __restrict__ dinv, int n) {
    int i = blockIdx.x * blockDim.x + threadIdx.x;
    if (i < n) {
        int d = (i < NN) ? cnt[i] : 0;
        dinv[i] = (d > 0) ? rsqrtf((float)d) : 0.0f;
    }
}

// ---- fused prep: pack x panel-major into buf panels 8..11, W->WT bf16, biases ----
__global__ void prep_kernel(const void* __restrict__ x,
                            const void* __restrict__ W1, const void* __restrict__ W2,
                            const void* __restrict__ W3, const void* __restrict__ b1,
                            const void* __restrict__ b2, const void* __restrict__ b3,
                            unsigned short* __restrict__ buf,
                            unsigned short* __restrict__ WT1, unsigned short* __restrict__ WT2,
                            unsigned short* __restrict__ WT3, unsigned short* __restrict__ bb1,
                            unsigned short* __restrict__ bb2, unsigned short* __restrict__ bb3,
                            const int* __restrict__ modep) {
    int mode = *modep;
    int b = blockIdx.x, t = threadIdx.x;
    if (b < 3125) {                                   // pack x: NN*16 uint4 chunks
        int idx = b * 256 + t;                        // idx < 800000
        int n = idx >> 4, c = idx & 15;               // c: 16 chunks of 8 features
        uint4* dp = (uint4*)(buf + (size_t)(8 + (c >> 2)) * PSTR + (size_t)n * 32 + (c & 3) * 8);
        if (mode == 0) {
            *dp = ((const uint4*)x)[idx];
        } else {
            const float* xf = (const float*)x + (size_t)idx * 8;
            unsigned short o[8];
#pragma unroll
            for (int i = 0; i < 8; ++i) o[i] = f2b(xf[i]);
            *dp = *(const uint4*)o;
        }
    } else if (b < 3381) {                            // WT1 [256][256] from W1[256][256]
        int idx = (b - 3125) * 256 + t;
        int n = idx >> 8, k = idx & 255;
        WT1[idx] = mode ? f2b(((const float*)W1)[k * 256 + n])
                        : ((const unsigned short*)W1)[k * 256 + n];
    } else if (b < 3893) {                            // WT2 [256][512] from W2[512][256]
        int idx = (b - 3381) * 256 + t;
        int n = idx >> 9, k = idx & 511;
        WT2[idx] = mode ? f2b(((const float*)W2)[k * 256 + n])
                        : ((const unsigned short*)W2)[k * 256 + n];
    } else if (b < 4149) {                            // WT3 [128][512] from W3[512][128]
        int idx = (b - 3893) * 256 + t;
        int n = idx >> 9, k = idx & 511;
        WT3[idx] = mode ? f2b(((const float*)W3)[k * 128 + n])
                        : ((const unsigned short*)W3)[k * 128 + n];
    } else {                                          // biases + zero sentinel rows
        if (t < 256) {
            bb1[t] = mode ? f2b(((const float*)b1)[t]) : ((const unsigned short*)b1)[t];
            bb2[t] = mode ? f2b(((const float*)b2)[t]) : ((const unsigned short*)b2)[t];
        }
        if (t < 128)
            bb3[t] = mode ? f2b(((const float*)b3)[t]) : ((const unsigned short*)b3)[t];
        if (t < 32) {
#pragma unroll
            for (int pnl = 0; pnl < 16; ++pnl)
                buf[(size_t)pnl * PSTR + (size_t)NN * 32 + t] = 0;
        }
    }
}

// ---- SpMM, XCD-panel-pinned, group-per-node, reduce-free, pipelined ----
// hp/outp: [NP][NR][32] bf16 panels. panel = blockIdx % NP keeps each XCD's random
// gathers inside ONE 3.2MB panel. ELL/cnt are streamed NON-TEMPORAL (evict-first)
// and the output store is non-temporal, so panel + dinv (3.4MB) stay L2-resident.
// Wave = 8 nodes x 8 feature-quads; accumulators lane-private (no reduce).
// Per 8-edge batch: next batch's ELL entry is prefetched BEFORE the gather loop,
// its dinv gather issued AFTER (so it never blocks h-gather issue) -> the
// ELL->dinv->shfl chain is hidden under the current batch's FMA work.
// Empty ELL slots = sentinel row NN (dinv=0, row zeroed) -> no predication.
template <int NP>
__global__ void spmm_kernel(const unsigned short* __restrict__ hp,
                            const int* __restrict__ cnt,
                            const unsigned short* __restrict__ ell,
                            const float* __restrict__ dinv,
                            unsigned short* __restrict__ outp) {
    const int panel = blockIdx.x & (NP - 1);
    const int grp   = blockIdx.x / NP;
    const int lane  = threadIdx.x & 63;
    const int wave  = threadIdx.x >> 6;
    const int m     = lane & 7;           // feature-quad / edge-slot member
    const int gbase = lane & 56;          // first lane of my group
    const unsigned short* hb = hp + (size_t)panel * PSTR;
    unsigned short* ob = outp + (size_t)panel * PSTR;
    const int node = grp * 32 + wave * 8 + (lane >> 3);
    if (node >= NN) return;

    int c = __builtin_nontemporal_load(&cnt[node]); c = (c < CAP) ? c : CAP;
    int   w  = (int)__builtin_nontemporal_load(&ell[node * CAP + m]);  // batch 0
    float dm = dinv[w];
    float a0 = 0.f, a1 = 0.f, a2 = 0.f, a3 = 0.f;
    for (int e = 0; e < c; e += 8) {
        int wn = NN;
        bool more = (e + 8 < c);
        if (more) wn = (int)__builtin_nontemporal_load(&ell[node * CAP + e + 8 + m]);
#pragma unroll
        for (int j = 0; j < 8; ++j) {
            int   s = __shfl(w,  gbase + j);
            float d = __shfl(dm, gbase + j);
            const ushort4 v = *(const ushort4*)(hb + ((size_t)s << 5) + (m << 2));
            a0 += d * b2f(v.x); a1 += d * b2f(v.y);
            a2 += d * b2f(v.z); a3 += d * b2f(v.w);
        }
        float dmn = more ? dinv[wn] : 0.f;   // issued after the 8 gathers
        w = wn; dm = dmn;
    }
    float dn = -dinv[node];
    unsigned long long o =
          (unsigned long long)f2b(a0 * dn)
        | ((unsigned long long)f2b(a1 * dn) << 16)
        | ((unsigned long long)f2b(a2 * dn) << 32)
        | ((unsigned long long)f2b(a3 * dn) << 48);
    __builtin_nontemporal_store(
        o, (unsigned long long*)(ob + ((size_t)node << 5) + (m << 2)));
}

// ---- LDS-staged MFMA GEMM, 128(M) x NQ*64(N) block tile, 2*NQ waves ----
// A is panel-major [K32][NR][32]: the A-tile per K-step is one contiguous 8KB
// block (perfect global_load_lds staging). Block covers full output width ->
// owns its rows -> in-place safe.
template <int K32, int NQ>
__global__ void gemm_lds_kernel(const unsigned short* __restrict__ A,   // panel-major
                                const unsigned short* __restrict__ WT,  // [NQ*64 x K] bf16
                                const unsigned short* __restrict__ bias,
                                void* __restrict__ out, int ldo,
                                int M, int dotanh, int is_final, const int* __restrict__ modep) {
    constexpr int K    = K32 * 32;
    constexpr int NB   = NQ * 64;
    constexpr int NTHR = 2 * NQ * 64;
    constexpr int ACH  = 128 * 4;                     // 16B chunks of A tile
    constexpr int BCH  = NB * 4;
    constexpr int ROUNDS = (ACH + BCH) / NTHR;        // A/B boundary falls on a round edge
    __shared__ unsigned short lds[(128 + NB) * 32];   // A[128][32] then B[NB][32]

    const int tid = threadIdx.x;
    const int wave = tid >> 6, lane = tid & 63, quad = lane >> 4, l16 = lane & 15;
    const int mh = wave / NQ, nq = wave % NQ;
    const int m0 = blockIdx.x * 128;

    v4f acc[4][4];
#pragma unroll
    for (int mi = 0; mi < 4; ++mi)
#pragma unroll
        for (int ni = 0; ni < 4; ++ni) acc[mi][ni] = (v4f){0.f, 0.f, 0.f, 0.f};

    const unsigned short* gp[ROUNDS];
#pragma unroll
    for (int r = 0; r < ROUNDS; ++r) {
        int c = tid + r * NTHR;
        if (c < ACH) {
            int row = m0 + (c >> 2);
            if (row >= M) row = M - 1;
            gp[r] = A + (size_t)row * 32 + (c & 3) * 8;          // panel 0 base
        } else {
            int cb = c - ACH;
            gp[r] = WT + (size_t)(cb >> 2) * K + (cb & 3) * 8;
        }
    }

    const unsigned short* aT = lds;
    const unsigned short* bT = lds + 128 * 32;

    int koffA = 0, koffB = 0;   // A advances one panel per K-step; B advances 32
    for (int k0 = 0; k0 < K; k0 += 32) {
#pragma unroll
        for (int r = 0; r < ROUNDS; ++r) {
            int c = tid + r * NTHR;
            gld16(gp[r] + ((r * NTHR) < ACH ? koffA : koffB), (void*)&lds[c * 8]);
        }
        koffA += PSTR; koffB += 32;
        __syncthreads();

        v8s a_frag[4], b_frag[4];
#pragma unroll
        for (int mi = 0; mi < 4; ++mi)
            a_frag[mi] = *(const v8s*)&aT[(mh * 64 + mi * 16 + l16) * 32 + quad * 8];
#pragma unroll
        for (int ni = 0; ni < 4; ++ni)
            b_frag[ni] = *(const v8s*)&bT[(nq * 64 + ni * 16 + l16) * 32 + quad * 8];
#pragma unroll
        for (int mi = 0; mi < 4; ++mi)
#pragma unroll
            for (int ni = 0; ni < 4; ++ni)
                acc[mi][ni] = __builtin_amdgcn_mfma_f32_16x16x32_bf16(a_frag[mi], b_frag[ni],
                                                                      acc[mi][ni], 0, 0, 0);
        __syncthreads();
    }

    // fin: 0 = non-final (panel-major bf16), 1 = final bf16 row-major, 2 = final f32
    int fin = is_final ? (*modep ? 2 : 1) : 0;
#pragma unroll
    for (int ni = 0; ni < 4; ++ni) {
        int colc = nq * 64 + ni * 16 + l16;
        float bv = b2f(bias[colc]);
        size_t pbase = (size_t)(colc >> 5) * PSTR + (colc & 31);
#pragma unroll
        for (int mi = 0; mi < 4; ++mi) {
#pragma unroll
            for (int r = 0; r < 4; ++r) {
                int row = m0 + mh * 64 + mi * 16 + quad * 4 + r;
                if (row < M) {
                    float v = acc[mi][ni][r] + bv;
                    if (dotanh) v = tanhf(v);
                    if (fin == 2)      ((float*)out)[(size_t)row * ldo + colc] = v;
                    else if (fin == 1) ((unsigned short*)out)[(size_t)row * ldo + colc] = f2b(v);
                    else               ((unsigned short*)out)[pbase + ((size_t)row << 5)] = f2b(v);
                }
            }
        }
    }
}

static inline size_t al256(size_t x) { return (x + 255) & ~(size_t)255; }

extern "C" void kernel_launch(void* const* d_in, const int* in_sizes, int n_in,
                              void* d_out, int out_size, void* d_ws, size_t ws_size,
                              hipStream_t stream) {
    const void* x  = d_in[0];
    const int* src = (const int*)d_in[1];
    const int* dst = (const int*)d_in[2];
    const void* W1 = d_in[3]; const void* b1 = d_in[4];
    const void* W2 = d_in[5]; const void* b2 = d_in[6];
    const void* W3 = d_in[7]; const void* b3 = d_in[8];
    const int E = in_sizes[1];

    // workspace carve-up (~58.6 MB)
    char* p = (char*)d_ws;
    int* mode     = (int*)p;            p += 256;
    int* cnt      = (int*)p;            p += al256((size_t)NN * 4);
    float* dinv   = (float*)p;          p += al256((size_t)(NN + 1) * 4);
    unsigned short* ell = (unsigned short*)p; p += al256((size_t)NN * CAP * 2);
    unsigned short* WT1 = (unsigned short*)p; p += al256((size_t)256 * 256 * 2);
    unsigned short* WT2 = (unsigned short*)p; p += al256((size_t)256 * 512 * 2);
    unsigned short* WT3 = (unsigned short*)p; p += al256((size_t)128 * 512 * 2);
    unsigned short* bb1 = (unsigned short*)p; p += al256((size_t)256 * 2);
    unsigned short* bb2 = (unsigned short*)p; p += al256((size_t)256 * 2);
    unsigned short* bb3 = (unsigned short*)p; p += al256((size_t)128 * 2);
    unsigned short* buf = (unsigned short*)p; p += al256((size_t)16 * PSTR * 2);
    // buf: 16 panels of [NR][32] bf16. Panels 0..7 = h (GEMM output),
    // panels 8..15 = staging: L1 uses 8..11 = x, 12..15 = x1; L2+ use 8..15 = x1.

    hipMemsetAsync(cnt, 0, (size_t)NN * 4, stream);
    sniff_kernel<<<1, 64, 0, stream>>>((const unsigned short*)x, mode);
    prep_kernel<<<4150, 256, 0, stream>>>(x, W1, W2, W3, b1, b2, b3,
                                          buf, WT1, WT2, WT3, bb1, bb2, bb3, mode);
    int eb = (E + 255) / 256;
    fill_kernel<<<eb, 256, 0, stream>>>(src, dst, cnt, ell, E);
    pad_kernel<<<(NN + 3) / 4, 256, 0, stream>>>(cnt, ell);
    dinv_kernel<<<(NN + 256) / 256, 256, 0, stream>>>(cnt, dinv, NN + 1);

    const int NG  = (NN + 31) / 32;        // node-groups per panel (1563)
    const int GB  = (NN + 127) / 128;      // 391 gemm row-blocks

    // L1: x in panels 8..11 -> x1 panels 12..15; gemm K=256 over panels 8..15 -> h (0..7)
    spmm_kernel<4><<<4 * NG, 256, 0, stream>>>(buf + (size_t)8 * PSTR, cnt, ell, dinv,
                                               buf + (size_t)12 * PSTR);
    gemm_lds_kernel<8, 4><<<GB, 512, 0, stream>>>(buf + (size_t)8 * PSTR, WT1, bb1,
                                                  buf, 0, NN, 1, 0, mode);
    // L2..L4: h panels 0..7 -> x1 panels 8..15; gemm K=512 over panels 0..15 -> h (0..7)
    spmm_kernel<8><<<8 * NG, 256, 0, stream>>>(buf, cnt, ell, dinv, buf + (size_t)8 * PSTR);
    gemm_lds_kernel<16, 4><<<GB, 512, 0, stream>>>(buf, WT2, bb2, buf, 0, NN, 1, 0, mode);
    spmm_kernel<8><<<8 * NG, 256, 0, stream>>>(buf, cnt, ell, dinv, buf + (size_t)8 * PSTR);
    gemm_lds_kernel<16, 4><<<GB, 512, 0, stream>>>(buf, WT2, bb2, buf, 0, NN, 1, 0, mode);
    spmm_kernel<8><<<8 * NG, 256, 0, stream>>>(buf, cnt, ell, dinv, buf + (size_t)8 * PSTR);
    gemm_lds_kernel<16, 4><<<GB, 512, 0, stream>>>(buf, WT2, bb2, buf, 0, NN, 1, 0, mode);
    // L5 (no tanh) -> d_out (50000 x 128, bf16 or fp32 per mode)
    spmm_kernel<8><<<8 * NG, 256, 0, stream>>>(buf, cnt, ell, dinv, buf + (size_t)8 * PSTR);
    gemm_lds_kernel<16, 2><<<GB, 256, 0, stream>>>(buf, WT3, bb3, d_out, 128, NN, 0, 1, mode);
}

// Round 5
// 554.947 us; speedup vs baseline: 1.5435x; 1.5435x over previous
//
#include <hip/hip_runtime.h>
#include <cmath>

#define NN 50000
#define CAP 64               // ELL capacity; P(deg > 64 anywhere) ~ 1e-16 for E=800k

typedef short v8s __attribute__((ext_vector_type(8)));   // 8 x bf16 (4 VGPRs)
typedef float v4f __attribute__((ext_vector_type(4)));

__device__ __forceinline__ float b2f(unsigned short u) {
    return __uint_as_float(((unsigned int)u) << 16);
}
__device__ __forceinline__ unsigned short f2b(float f) {
    unsigned int x = __float_as_uint(f);
    x += 0x7fffu + ((x >> 16) & 1u);          // round-to-nearest-even
    return (unsigned short)(x >> 16);
}

// async global->LDS, 16B per lane. LDS dest must be wave-contiguous (base + lane*16).
__device__ __forceinline__ void gld16(const void* g, void* l) {
    __builtin_amdgcn_global_load_lds(
        (const __attribute__((address_space(1))) unsigned int*)g,
        (__attribute__((address_space(3))) unsigned int*)l, 16, 0, 0);
}

// ---- dtype sniffer: mode=0 -> inputs are bf16, mode=1 -> inputs are float32 ----
__global__ void sniff_kernel(const unsigned short* __restrict__ x, int* __restrict__ mode) {
    if (threadIdx.x == 0 && blockIdx.x == 0) {
        int c = 0;
        for (int i = 0; i < 128; ++i) {
            unsigned int e = (x[i] >> 7) & 0xFFu;
            if (e >= 100u && e <= 140u) ++c;
        }
        *mode = (c >= 112) ? 0 : 1;
    }
}

// ---- ELL fill: one atomic pass, no scan ----
__global__ void fill_kernel(const int* __restrict__ src, const int* __restrict__ dst,
                            int* __restrict__ cnt, unsigned short* __restrict__ ell, int E) {
    int e = blockIdx.x * blockDim.x + threadIdx.x;
    if (e < E) {
        int d = dst[e];
        int pos = atomicAdd(&cnt[d], 1);
        if (pos < CAP) ell[d * CAP + pos] = (unsigned short)src[e];
    }
}

// ---- dinv from counts ----
__global__ void dinv_kernel(const int* __restrict__ cnt, float* __restrict__ dinv, int n) {
    int i = blockIdx.x * blockDim.x + threadIdx.x;
    if (i < n) {
        int d = cnt[i];
        dinv[i] = (d > 0) ? rsqrtf((float)d) : 0.0f;
    }
}

// ---- fused prep: pack x into buf cols 0:128 (ld 512), W->WT bf16, biases ----
__global__ void prep_kernel(const void* __restrict__ x,
                            const void* __restrict__ W1, const void* __restrict__ W2,
                            const void* __restrict__ W3, const void* __restrict__ b1,
                            const void* __restrict__ b2, const void* __restrict__ b3,
                            unsigned short* __restrict__ buf,
                            unsigned short* __restrict__ WT1, unsigned short* __restrict__ WT2,
                            unsigned short* __restrict__ WT3, unsigned short* __restrict__ bb1,
                            unsigned short* __restrict__ bb2, unsigned short* __restrict__ bb3,
                            const int* __restrict__ modep) {
    int mode = *modep;
    int b = blockIdx.x, t = threadIdx.x;
    if (b < 3125) {                                   // pack x: NN*16 uint4 chunks
        int idx = b * 256 + t;                        // idx < 800000
        int n = idx >> 4, c = idx & 15;
        if (mode == 0) {
            ((uint4*)buf)[n * 64 + c] = ((const uint4*)x)[idx];
        } else {
            const float* xf = (const float*)x + (size_t)idx * 8;
            unsigned short o[8];
#pragma unroll
            for (int i = 0; i < 8; ++i) o[i] = f2b(xf[i]);
            ((uint4*)buf)[n * 64 + c] = *(const uint4*)o;
        }
    } else if (b < 3381) {                            // WT1 [256][256] from W1[256][256]
        int idx = (b - 3125) * 256 + t;
        int n = idx >> 8, k = idx & 255;
        WT1[idx] = mode ? f2b(((const float*)W1)[k * 256 + n])
                        : ((const unsigned short*)W1)[k * 256 + n];
    } else if (b < 3893) {                            // WT2 [256][512] from W2[512][256]
        int idx = (b - 3381) * 256 + t;
        int n = idx >> 9, k = idx & 511;
        WT2[idx] = mode ? f2b(((const float*)W2)[k * 256 + n])
                        : ((const unsigned short*)W2)[k * 256 + n];
    } else if (b < 4149) {                            // WT3 [128][512] from W3[512][128]
        int idx = (b - 3893) * 256 + t;
        int n = idx >> 9, k = idx & 511;
        WT3[idx] = mode ? f2b(((const float*)W3)[k * 128 + n])
                        : ((const unsigned short*)W3)[k * 128 + n];
    } else {                                          // biases
        if (t < 256) {
            bb1[t] = mode ? f2b(((const float*)b1)[t]) : ((const unsigned short*)b1)[t];
            bb2[t] = mode ? f2b(((const float*)b2)[t]) : ((const unsigned short*)b2)[t];
        }
        if (t < 128)
            bb3[t] = mode ? f2b(((const float*)b3)[t]) : ((const unsigned short*)b3)[t];
    }
}

// ---- SpMM (ELL): one wave per dst node; x1[n] = -dinv[n] * sum_e dinv[src]*h[src]
// Wave loads its <=64 ELL entries once (coalesced 128B) + one dinv gather, then
// broadcasts via shfl and issues 16 independent row-gathers per batch (deep MLP:
// avg degree 16 -> a typical node has ALL gathers in flight at once).
// Tail: masked batch of 16 where padding lanes replicate edge g with weight 0 —
// duplicate address = L1 hit, near-free.
template <int FPL>   // features per lane: F = 64*FPL (2 -> 128, 4 -> 256)
__global__ void spmm_kernel(const unsigned short* __restrict__ h, int ldh,
                            const int* __restrict__ cnt, const unsigned short* __restrict__ ell,
                            const float* __restrict__ dinv,
                            unsigned short* __restrict__ out, int ldo) {
    int node = blockIdx.x * 4 + (threadIdx.x >> 6);
    int lane = threadIdx.x & 63;
    int c = cnt[node]; c = (c < CAP) ? c : CAP;
    int sl = (int)ell[node * CAP + lane];      // coalesced; lanes >= c hold junk (unused)
    float dl = dinv[sl];
    float acc[FPL];
#pragma unroll
    for (int i = 0; i < FPL; ++i) acc[i] = 0.f;
    const int col = lane * FPL;

    int g = 0;
    for (; g + 16 <= c; g += 16) {
        int s[16]; float d[16];
#pragma unroll
        for (int i = 0; i < 16; ++i) { s[i] = __shfl(sl, g + i); d[i] = __shfl(dl, g + i); }
        if (FPL == 4) {
            ushort4 v[16];
#pragma unroll
            for (int i = 0; i < 16; ++i)
                v[i] = *(const ushort4*)(h + (size_t)s[i] * ldh + col);
#pragma unroll
            for (int i = 0; i < 16; ++i) {
                acc[0] += d[i] * b2f(v[i].x); acc[1] += d[i] * b2f(v[i].y);
                acc[2] += d[i] * b2f(v[i].z); acc[3] += d[i] * b2f(v[i].w);
            }
        } else {
            ushort2 v[16];
#pragma unroll
            for (int i = 0; i < 16; ++i)
                v[i] = *(const ushort2*)(h + (size_t)s[i] * ldh + col);
#pragma unroll
            for (int i = 0; i < 16; ++i) {
                acc[0] += d[i] * b2f(v[i].x); acc[1] += d[i] * b2f(v[i].y);
            }
        }
    }
    if (g < c) {                      // masked tail batch (r = c-g in 1..15)
        int s[16]; float d[16];
#pragma unroll
        for (int i = 0; i < 16; ++i) {
            int idx = g + i;
            bool ok = idx < c;
            int j = ok ? idx : g;     // wave-uniform select
            s[i] = __shfl(sl, j);
            float dd = __shfl(dl, j);
            d[i] = ok ? dd : 0.f;
        }
        if (FPL == 4) {
            ushort4 v[16];
#pragma unroll
            for (int i = 0; i < 16; ++i)
                v[i] = *(const ushort4*)(h + (size_t)s[i] * ldh + col);
#pragma unroll
            for (int i = 0; i < 16; ++i) {
                acc[0] += d[i] * b2f(v[i].x); acc[1] += d[i] * b2f(v[i].y);
                acc[2] += d[i] * b2f(v[i].z); acc[3] += d[i] * b2f(v[i].w);
            }
        } else {
            ushort2 v[16];
#pragma unroll
            for (int i = 0; i < 16; ++i)
                v[i] = *(const ushort2*)(h + (size_t)s[i] * ldh + col);
#pragma unroll
            for (int i = 0; i < 16; ++i) {
                acc[0] += d[i] * b2f(v[i].x); acc[1] += d[i] * b2f(v[i].y);
            }
        }
    }

    float dn = -dinv[node];
    unsigned short* op = out + (size_t)node * ldo + col;
    if (FPL == 4) {
        ushort4 o;
        o.x = f2b(acc[0] * dn); o.y = f2b(acc[1] * dn);
        o.z = f2b(acc[2] * dn); o.w = f2b(acc[3] * dn);
        *(ushort4*)op = o;
    } else {
        ushort2 o;
        o.x = f2b(acc[0] * dn); o.y = f2b(acc[1] * dn);
        *(ushort2*)op = o;
    }
}

// ---- LDS-staged MFMA GEMM, 128(M) x NQ*64(N) block tile, 2*NQ waves ----
// Wave w: rows (w/NQ)*64..+64, cols (w%NQ)*64..+64; 4x4 mfma tiles, acc 64 VGPR.
// Block covers full output width -> owns its rows -> in-place safe (all K-loop
// A reads complete before epilogue stores).
template <int K32, int NQ>
__global__ void gemm_lds_kernel(const unsigned short* __restrict__ A, int lda,
                                const unsigned short* __restrict__ WT,   // [NQ*64 x K] bf16
                                const unsigned short* __restrict__ bias, // bf16
                                void* __restrict__ out, int ldo,
                                int M, int dotanh, int is_final, const int* __restrict__ modep) {
    constexpr int K    = K32 * 32;
    constexpr int NB   = NQ * 64;
    constexpr int NTHR = 2 * NQ * 64;
    constexpr int ACH  = 128 * 4;                     // 16B chunks of A tile
    constexpr int BCH  = NB * 4;
    constexpr int ROUNDS = (ACH + BCH) / NTHR;
    __shared__ unsigned short lds[(128 + NB) * 32];   // A[128][32] then B[NB][32]

    const int tid = threadIdx.x;
    const int wave = tid >> 6, lane = tid & 63, quad = lane >> 4, l16 = lane & 15;
    const int mh = wave / NQ, nq = wave % NQ;
    const int m0 = blockIdx.x * 128;

    v4f acc[4][4];
#pragma unroll
    for (int mi = 0; mi < 4; ++mi)
#pragma unroll
        for (int ni = 0; ni < 4; ++ni) acc[mi][ni] = (v4f){0.f, 0.f, 0.f, 0.f};

    const unsigned short* gp[ROUNDS];
#pragma unroll
    for (int r = 0; r < ROUNDS; ++r) {
        int c = tid + r * NTHR;
        if (c < ACH) {
            int row = m0 + (c >> 2);
            if (row >= M) row = M - 1;
            gp[r] = A + (size_t)row * lda + (c & 3) * 8;
        } else {
            int cb = c - ACH;
            gp[r] = WT + (size_t)(cb >> 2) * K + (cb & 3) * 8;
        }
    }

    const unsigned short* aT = lds;
    const unsigned short* bT = lds + 128 * 32;

    for (int k0 = 0; k0 < K; k0 += 32) {
#pragma unroll
        for (int r = 0; r < ROUNDS; ++r) {
            int c = tid + r * NTHR;
            gld16(gp[r] + k0, (void*)&lds[c * 8]);
        }
        __syncthreads();

        v8s a_frag[4], b_frag[4];
#pragma unroll
        for (int mi = 0; mi < 4; ++mi)
            a_frag[mi] = *(const v8s*)&aT[(mh * 64 + mi * 16 + l16) * 32 + quad * 8];
#pragma unroll
        for (int ni = 0; ni < 4; ++ni)
            b_frag[ni] = *(const v8s*)&bT[(nq * 64 + ni * 16 + l16) * 32 + quad * 8];
#pragma unroll
        for (int mi = 0; mi < 4; ++mi)
#pragma unroll
            for (int ni = 0; ni < 4; ++ni)
                acc[mi][ni] = __builtin_amdgcn_mfma_f32_16x16x32_bf16(a_frag[mi], b_frag[ni],
                                                                      acc[mi][ni], 0, 0, 0);
        __syncthreads();
    }

    int fin = is_final ? *modep : 0;
#pragma unroll
    for (int ni = 0; ni < 4; ++ni) {
        int colc = nq * 64 + ni * 16 + l16;
        float bv = b2f(bias[colc]);
#pragma unroll
        for (int mi = 0; mi < 4; ++mi) {
#pragma unroll
            for (int r = 0; r < 4; ++r) {
                int row = m0 + mh * 64 + mi * 16 + quad * 4 + r;
                if (row < M) {
                    float v = acc[mi][ni][r] + bv;
                    if (dotanh) v = tanhf(v);
                    if (fin) ((float*)out)[(size_t)row * ldo + colc] = v;
                    else     ((unsigned short*)out)[(size_t)row * ldo + colc] = f2b(v);
                }
            }
        }
    }
}

static inline size_t al256(size_t x) { return (x + 255) & ~(size_t)255; }

extern "C" void kernel_launch(void* const* d_in, const int* in_sizes, int n_in,
                              void* d_out, int out_size, void* d_ws, size_t ws_size,
                              hipStream_t stream) {
    const void* x  = d_in[0];
    const int* src = (const int*)d_in[1];
    const int* dst = (const int*)d_in[2];
    const void* W1 = d_in[3]; const void* b1 = d_in[4];
    const void* W2 = d_in[5]; const void* b2 = d_in[6];
    const void* W3 = d_in[7]; const void* b3 = d_in[8];
    const int E = in_sizes[1];

    // workspace carve-up (~58.6 MB)
    char* p = (char*)d_ws;
    int* mode     = (int*)p;            p += 256;
    int* cnt      = (int*)p;            p += al256((size_t)NN * 4);
    float* dinv   = (float*)p;          p += al256((size_t)NN * 4);
    unsigned short* ell = (unsigned short*)p; p += al256((size_t)NN * CAP * 2);
    unsigned short* WT1 = (unsigned short*)p; p += al256((size_t)256 * 256 * 2);
    unsigned short* WT2 = (unsigned short*)p; p += al256((size_t)256 * 512 * 2);
    unsigned short* WT3 = (unsigned short*)p; p += al256((size_t)128 * 512 * 2);
    unsigned short* bb1 = (unsigned short*)p; p += al256((size_t)256 * 2);
    unsigned short* bb2 = (unsigned short*)p; p += al256((size_t)256 * 2);
    unsigned short* bb3 = (unsigned short*)p; p += al256((size_t)128 * 2);
    unsigned short* buf = (unsigned short*)p; p += al256((size_t)NN * 512 * 2);

    hipMemsetAsync(cnt, 0, (size_t)NN * 4, stream);
    sniff_kernel<<<1, 64, 0, stream>>>((const unsigned short*)x, mode);
    prep_kernel<<<4150, 256, 0, stream>>>(x, W1, W2, W3, b1, b2, b3,
                                          buf, WT1, WT2, WT3, bb1, bb2, bb3, mode);
    int eb = (E + 255) / 256;
    fill_kernel<<<eb, 256, 0, stream>>>(src, dst, cnt, ell, E);
    dinv_kernel<<<(NN + 255) / 256, 256, 0, stream>>>(cnt, dinv, NN);

    const int SPMM_GRID = NN / 4;          // 4 waves (nodes) per 256-thread block
    const int GB = (NN + 127) / 128;       // 391 gemm row-blocks

    // L1: buf = [x(0:128) | x1(128:256)]; gemm K=256 in-place -> cols 0:256
    spmm_kernel<2><<<SPMM_GRID, 256, 0, stream>>>(buf, 512, cnt, ell, dinv, buf + 128, 512);
    gemm_lds_kernel<8, 4><<<GB, 512, 0, stream>>>(buf, 512, WT1, bb1, buf, 512, NN, 1, 0, mode);
    // L2..L4: x1 into cols 256:512, gemm K=512 in-place -> cols 0:256
    spmm_kernel<4><<<SPMM_GRID, 256, 0, stream>>>(buf, 512, cnt, ell, dinv, buf + 256, 512);
    gemm_lds_kernel<16, 4><<<GB, 512, 0, stream>>>(buf, 512, WT2, bb2, buf, 512, NN, 1, 0, mode);
    spmm_kernel<4><<<SPMM_GRID, 256, 0, stream>>>(buf, 512, cnt, ell, dinv, buf + 256, 512);
    gemm_lds_kernel<16, 4><<<GB, 512, 0, stream>>>(buf, 512, WT2, bb2, buf, 512, NN, 1, 0, mode);
    spmm_kernel<4><<<SPMM_GRID, 256, 0, stream>>>(buf, 512, cnt, ell, dinv, buf + 256, 512);
    gemm_lds_kernel<16, 4><<<GB, 512, 0, stream>>>(buf, 512, WT2, bb2, buf, 512, NN, 1, 0, mode);
    // L5 (no tanh) -> d_out (50000 x 128, bf16 or fp32 per mode)
    spmm_kernel<4><<<SPMM_GRID, 256, 0, stream>>>(buf, 512, cnt, ell, dinv, buf + 256, 512);
    gemm_lds_kernel<16, 2><<<GB, 256, 0, stream>>>(buf, 512, WT3, bb3, d_out, 128, NN, 0, 1, mode);
}

// Round 6
// 545.719 us; speedup vs baseline: 1.5696x; 1.0169x over previous
//
#include <hip/hip_runtime.h>
#include <cmath>

#define NN 50000
#define CAP 64               // ELL capacity; P(deg > 64 anywhere) ~ 1e-16 for E=800k

typedef short v8s __attribute__((ext_vector_type(8)));   // 8 x bf16 (4 VGPRs)
typedef float v4f __attribute__((ext_vector_type(4)));

__device__ __forceinline__ float b2f(unsigned short u) {
    return __uint_as_float(((unsigned int)u) << 16);
}
__device__ __forceinline__ unsigned short f2b(float f) {
    unsigned int x = __float_as_uint(f);
    x += 0x7fffu + ((x >> 16) & 1u);          // round-to-nearest-even
    return (unsigned short)(x >> 16);
}

// async global->LDS, 16B per lane. LDS dest must be wave-contiguous (base + lane*16).
__device__ __forceinline__ void gld16(const void* g, void* l) {
    __builtin_amdgcn_global_load_lds(
        (const __attribute__((address_space(1))) unsigned int*)g,
        (__attribute__((address_space(3))) unsigned int*)l, 16, 0, 0);
}

// ---- dtype sniffer: mode=0 -> inputs are bf16, mode=1 -> inputs are float32 ----
__global__ void sniff_kernel(const unsigned short* __restrict__ x, int* __restrict__ mode) {
    if (threadIdx.x == 0 && blockIdx.x == 0) {
        int c = 0;
        for (int i = 0; i < 128; ++i) {
            unsigned int e = (x[i] >> 7) & 0xFFu;
            if (e >= 100u && e <= 140u) ++c;
        }
        *mode = (c >= 112) ? 0 : 1;
    }
}

// ---- ELL fill: one atomic pass, no scan ----
__global__ void fill_kernel(const int* __restrict__ src, const int* __restrict__ dst,
                            int* __restrict__ cnt, unsigned short* __restrict__ ell, int E) {
    int e = blockIdx.x * blockDim.x + threadIdx.x;
    if (e < E) {
        int d = dst[e];
        int pos = atomicAdd(&cnt[d], 1);
        if (pos < CAP) ell[d * CAP + pos] = (unsigned short)src[e];
    }
}

// ---- dinv from counts ----
__global__ void dinv_kernel(const int* __restrict__ cnt, float* __restrict__ dinv, int n) {
    int i = blockIdx.x * blockDim.x + threadIdx.x;
    if (i < n) {
        int d = cnt[i];
        dinv[i] = (d > 0) ? rsqrtf((float)d) : 0.0f;
    }
}

// ---- fused prep: pack x into buf cols 0:128 (ld 512), W->WT bf16, biases ----
__global__ void prep_kernel(const void* __restrict__ x,
                            const void* __restrict__ W1, const void* __restrict__ W2,
                            const void* __restrict__ W3, const void* __restrict__ b1,
                            const void* __restrict__ b2, const void* __restrict__ b3,
                            unsigned short* __restrict__ buf,
                            unsigned short* __restrict__ WT1, unsigned short* __restrict__ WT2,
                            unsigned short* __restrict__ WT3, unsigned short* __restrict__ bb1,
                            unsigned short* __restrict__ bb2, unsigned short* __restrict__ bb3,
                            const int* __restrict__ modep) {
    int mode = *modep;
    int b = blockIdx.x, t = threadIdx.x;
    if (b < 3125) {                                   // pack x: NN*16 uint4 chunks
        int idx = b * 256 + t;                        // idx < 800000
        int n = idx >> 4, c = idx & 15;
        if (mode == 0) {
            ((uint4*)buf)[n * 64 + c] = ((const uint4*)x)[idx];
        } else {
            const float* xf = (const float*)x + (size_t)idx * 8;
            unsigned short o[8];
#pragma unroll
            for (int i = 0; i < 8; ++i) o[i] = f2b(xf[i]);
            ((uint4*)buf)[n * 64 + c] = *(const uint4*)o;
        }
    } else if (b < 3381) {                            // WT1 [256][256] from W1[256][256]
        int idx = (b - 3125) * 256 + t;
        int n = idx >> 8, k = idx & 255;
        WT1[idx] = mode ? f2b(((const float*)W1)[k * 256 + n])
                        : ((const unsigned short*)W1)[k * 256 + n];
    } else if (b < 3893) {                            // WT2 [256][512] from W2[512][256]
        int idx = (b - 3381) * 256 + t;
        int n = idx >> 9, k = idx & 511;
        WT2[idx] = mode ? f2b(((const float*)W2)[k * 256 + n])
                        : ((const unsigned short*)W2)[k * 256 + n];
    } else if (b < 4149) {                            // WT3 [128][512] from W3[512][128]
        int idx = (b - 3893) * 256 + t;
        int n = idx >> 9, k = idx & 511;
        WT3[idx] = mode ? f2b(((const float*)W3)[k * 128 + n])
                        : ((const unsigned short*)W3)[k * 128 + n];
    } else {                                          // biases
        if (t < 256) {
            bb1[t] = mode ? f2b(((const float*)b1)[t]) : ((const unsigned short*)b1)[t];
            bb2[t] = mode ? f2b(((const float*)b2)[t]) : ((const unsigned short*)b2)[t];
        }
        if (t < 128)
            bb3[t] = mode ? f2b(((const float*)b3)[t]) : ((const unsigned short*)b3)[t];
    }
}

// ---- SpMM (ELL): one wave per dst node; x1[n] = -dinv[n] * sum_e dinv[src]*h[src]
// Wave loads its <=64 ELL entries once (coalesced 128B) + one dinv gather, then
// broadcasts via shfl and issues 8 independent row-gathers per batch.
// (R5 measured: 16-deep batches change nothing — spmm is MSHR x latency capped —
//  so keep the 8-deep / 28-VGPR form.)
template <int FPL>   // features per lane: F = 64*FPL (2 -> 128, 4 -> 256)
__global__ void spmm_kernel(const unsigned short* __restrict__ h, int ldh,
                            const int* __restrict__ cnt, const unsigned short* __restrict__ ell,
                            const float* __restrict__ dinv,
                            unsigned short* __restrict__ out, int ldo) {
    int node = blockIdx.x * 4 + (threadIdx.x >> 6);
    int lane = threadIdx.x & 63;
    int c = cnt[node]; c = (c < CAP) ? c : CAP;
    int sl = (int)ell[node * CAP + lane];      // coalesced; lanes >= c hold junk (unused)
    float dl = dinv[sl];
    float acc[FPL];
#pragma unroll
    for (int i = 0; i < FPL; ++i) acc[i] = 0.f;
    const int col = lane * FPL;

    int g = 0;
    for (; g + 8 <= c; g += 8) {
        int s[8]; float d[8];
#pragma unroll
        for (int i = 0; i < 8; ++i) { s[i] = __shfl(sl, g + i); d[i] = __shfl(dl, g + i); }
        if (FPL == 4) {
            ushort4 v[8];
#pragma unroll
            for (int i = 0; i < 8; ++i)
                v[i] = *(const ushort4*)(h + (size_t)s[i] * ldh + col);
#pragma unroll
            for (int i = 0; i < 8; ++i) {
                acc[0] += d[i] * b2f(v[i].x); acc[1] += d[i] * b2f(v[i].y);
                acc[2] += d[i] * b2f(v[i].z); acc[3] += d[i] * b2f(v[i].w);
            }
        } else {
            ushort2 v[8];
#pragma unroll
            for (int i = 0; i < 8; ++i)
                v[i] = *(const ushort2*)(h + (size_t)s[i] * ldh + col);
#pragma unroll
            for (int i = 0; i < 8; ++i) {
                acc[0] += d[i] * b2f(v[i].x); acc[1] += d[i] * b2f(v[i].y);
            }
        }
    }
    for (; g < c; ++g) {
        int sg = __shfl(sl, g);
        float dg = __shfl(dl, g);
        const unsigned short* hp = h + (size_t)sg * ldh + col;
        if (FPL == 4) {
            ushort4 v = *(const ushort4*)hp;
            acc[0] += dg * b2f(v.x); acc[1] += dg * b2f(v.y);
            acc[2] += dg * b2f(v.z); acc[3] += dg * b2f(v.w);
        } else {
            ushort2 v = *(const ushort2*)hp;
            acc[0] += dg * b2f(v.x); acc[1] += dg * b2f(v.y);
        }
    }

    float dn = -dinv[node];
    unsigned short* op = out + (size_t)node * ldo + col;
    if (FPL == 4) {
        ushort4 o;
        o.x = f2b(acc[0] * dn); o.y = f2b(acc[1] * dn);
        o.z = f2b(acc[2] * dn); o.w = f2b(acc[3] * dn);
        *(ushort4*)op = o;
    } else {
        ushort2 o;
        o.x = f2b(acc[0] * dn); o.y = f2b(acc[1] * dn);
        *(ushort2*)op = o;
    }
}

// ---- LDS-staged MFMA GEMM, 128(M) x NQ*64(N) block tile, 2*NQ waves ----
// NOW double-buffered with counted vmcnt (T3 minimum-2-phase + T4): each iter
// issues STAGE(t+1) into the other LDS buffer FIRST, then waits vmcnt(ROUNDS)
// (t's loads done, t+1's stay in flight ACROSS the raw s_barrier — no
// __syncthreads, which would drain vmcnt(0)), computes tile t, lgkmcnt(0) +
// barrier (all waves done reading buf[t&1] before iter t+1 overwrites it).
// Block covers full output width -> owns its rows -> in-place safe (all K-loop
// A loads are issued and vmcnt-drained before epilogue stores).
template <int K32, int NQ>
__global__ void __launch_bounds__(2 * NQ * 64)
gemm_lds_kernel(const unsigned short* __restrict__ A, int lda,
                const unsigned short* __restrict__ WT,   // [NQ*64 x K] bf16
                const unsigned short* __restrict__ bias, // bf16
                void* __restrict__ out, int ldo,
                int M, int dotanh, int is_final, const int* __restrict__ modep) {
    constexpr int K    = K32 * 32;
    constexpr int NB   = NQ * 64;
    constexpr int NTHR = 2 * NQ * 64;
    constexpr int ACH  = 128 * 4;                     // 16B chunks of A tile
    constexpr int BCH  = NB * 4;
    constexpr int ROUNDS = (ACH + BCH) / NTHR;
    constexpr int LDSZ  = (128 + NB) * 32;            // ushorts per buffer
    __shared__ unsigned short lds[2 * LDSZ];          // double-buffered A|B tiles

    const int tid = threadIdx.x;
    const int wave = tid >> 6, lane = tid & 63, quad = lane >> 4, l16 = lane & 15;
    const int mh = wave / NQ, nq = wave % NQ;
    const int m0 = blockIdx.x * 128;

    v4f acc[4][4];
#pragma unroll
    for (int mi = 0; mi < 4; ++mi)
#pragma unroll
        for (int ni = 0; ni < 4; ++ni) acc[mi][ni] = (v4f){0.f, 0.f, 0.f, 0.f};

    const unsigned short* gp[ROUNDS];
#pragma unroll
    for (int r = 0; r < ROUNDS; ++r) {
        int c = tid + r * NTHR;
        if (c < ACH) {
            int row = m0 + (c >> 2);
            if (row >= M) row = M - 1;
            gp[r] = A + (size_t)row * lda + (c & 3) * 8;
        } else {
            int cb = c - ACH;
            gp[r] = WT + (size_t)(cb >> 2) * K + (cb & 3) * 8;
        }
    }

    auto STAGE = [&](int bsel, int k0) {
#pragma unroll
        for (int r = 0; r < ROUNDS; ++r) {
            int c = tid + r * NTHR;
            gld16(gp[r] + k0, (void*)&lds[bsel * LDSZ + c * 8]);
        }
    };

    STAGE(0, 0);                                      // prologue: tile 0 in flight
#pragma unroll 1
    for (int t = 0; t < K32; ++t) {
        if (t + 1 < K32) {
            STAGE((t + 1) & 1, (t + 1) * 32);         // issue next FIRST
            asm volatile("s_waitcnt vmcnt(%0)" :: "i"(ROUNDS) : "memory");  // t's landed
        } else {
            asm volatile("s_waitcnt vmcnt(0)" ::: "memory");
        }
        __builtin_amdgcn_s_barrier();                 // t's tile visible to all waves

        const unsigned short* aT = &lds[(t & 1) * LDSZ];
        const unsigned short* bT = aT + 128 * 32;
        v8s a_frag[4], b_frag[4];
#pragma unroll
        for (int mi = 0; mi < 4; ++mi)
            a_frag[mi] = *(const v8s*)&aT[(mh * 64 + mi * 16 + l16) * 32 + quad * 8];
#pragma unroll
        for (int ni = 0; ni < 4; ++ni)
            b_frag[ni] = *(const v8s*)&bT[(nq * 64 + ni * 16 + l16) * 32 + quad * 8];
#pragma unroll
        for (int mi = 0; mi < 4; ++mi)
#pragma unroll
            for (int ni = 0; ni < 4; ++ni)
                acc[mi][ni] = __builtin_amdgcn_mfma_f32_16x16x32_bf16(a_frag[mi], b_frag[ni],
                                                                      acc[mi][ni], 0, 0, 0);
        asm volatile("s_waitcnt lgkmcnt(0)" ::: "memory");   // my ds_reads retired
        __builtin_amdgcn_s_barrier();                 // safe to overwrite buf[t&1]
    }

    int fin = is_final ? *modep : 0;
#pragma unroll
    for (int ni = 0; ni < 4; ++ni) {
        int colc = nq * 64 + ni * 16 + l16;
        float bv = b2f(bias[colc]);
#pragma unroll
        for (int mi = 0; mi < 4; ++mi) {
#pragma unroll
            for (int r = 0; r < 4; ++r) {
                int row = m0 + mh * 64 + mi * 16 + quad * 4 + r;
                if (row < M) {
                    float v = acc[mi][ni][r] + bv;
                    if (dotanh) v = tanhf(v);
                    if (fin) ((float*)out)[(size_t)row * ldo + colc] = v;
                    else     ((unsigned short*)out)[(size_t)row * ldo + colc] = f2b(v);
                }
            }
        }
    }
}

static inline size_t al256(size_t x) { return (x + 255) & ~(size_t)255; }

extern "C" void kernel_launch(void* const* d_in, const int* in_sizes, int n_in,
                              void* d_out, int out_size, void* d_ws, size_t ws_size,
                              hipStream_t stream) {
    const void* x  = d_in[0];
    const int* src = (const int*)d_in[1];
    const int* dst = (const int*)d_in[2];
    const void* W1 = d_in[3]; const void* b1 = d_in[4];
    const void* W2 = d_in[5]; const void* b2 = d_in[6];
    const void* W3 = d_in[7]; const void* b3 = d_in[8];
    const int E = in_sizes[1];

    // workspace carve-up (~58.6 MB)
    char* p = (char*)d_ws;
    int* mode     = (int*)p;            p += 256;
    int* cnt      = (int*)p;            p += al256((size_t)NN * 4);
    float* dinv   = (float*)p;          p += al256((size_t)NN * 4);
    unsigned short* ell = (unsigned short*)p; p += al256((size_t)NN * CAP * 2);
    unsigned short* WT1 = (unsigned short*)p; p += al256((size_t)256 * 256 * 2);
    unsigned short* WT2 = (unsigned short*)p; p += al256((size_t)256 * 512 * 2);
    unsigned short* WT3 = (unsigned short*)p; p += al256((size_t)128 * 512 * 2);
    unsigned short* bb1 = (unsigned short*)p; p += al256((size_t)256 * 2);
    unsigned short* bb2 = (unsigned short*)p; p += al256((size_t)256 * 2);
    unsigned short* bb3 = (unsigned short*)p; p += al256((size_t)128 * 2);
    unsigned short* buf = (unsigned short*)p; p += al256((size_t)NN * 512 * 2);

    hipMemsetAsync(cnt, 0, (size_t)NN * 4, stream);
    sniff_kernel<<<1, 64, 0, stream>>>((const unsigned short*)x, mode);
    prep_kernel<<<4150, 256, 0, stream>>>(x, W1, W2, W3, b1, b2, b3,
                                          buf, WT1, WT2, WT3, bb1, bb2, bb3, mode);
    int eb = (E + 255) / 256;
    fill_kernel<<<eb, 256, 0, stream>>>(src, dst, cnt, ell, E);
    dinv_kernel<<<(NN + 255) / 256, 256, 0, stream>>>(cnt, dinv, NN);

    const int SPMM_GRID = NN / 4;          // 4 waves (nodes) per 256-thread block
    const int GB = (NN + 127) / 128;       // 391 gemm row-blocks

    // L1: buf = [x(0:128) | x1(128:256)]; gemm K=256 in-place -> cols 0:256
    spmm_kernel<2><<<SPMM_GRID, 256, 0, stream>>>(buf, 512, cnt, ell, dinv, buf + 128, 512);
    gemm_lds_kernel<8, 4><<<GB, 512, 0, stream>>>(buf, 512, WT1, bb1, buf, 512, NN, 1, 0, mode);
    // L2..L4: x1 into cols 256:512, gemm K=512 in-place -> cols 0:256
    spmm_kernel<4><<<SPMM_GRID, 256, 0, stream>>>(buf, 512, cnt, ell, dinv, buf + 256, 512);
    gemm_lds_kernel<16, 4><<<GB, 512, 0, stream>>>(buf, 512, WT2, bb2, buf, 512, NN, 1, 0, mode);
    spmm_kernel<4><<<SPMM_GRID, 256, 0, stream>>>(buf, 512, cnt, ell, dinv, buf + 256, 512);
    gemm_lds_kernel<16, 4><<<GB, 512, 0, stream>>>(buf, 512, WT2, bb2, buf, 512, NN, 1, 0, mode);
    spmm_kernel<4><<<SPMM_GRID, 256, 0, stream>>>(buf, 512, cnt, ell, dinv, buf + 256, 512);
    gemm_lds_kernel<16, 4><<<GB, 512, 0, stream>>>(buf, 512, WT2, bb2, buf, 512, NN, 1, 0, mode);
    // L5 (no tanh) -> d_out (50000 x 128, bf16 or fp32 per mode)
    spmm_kernel<4><<<SPMM_GRID, 256, 0, stream>>>(buf, 512, cnt, ell, dinv, buf + 256, 512);
    gemm_lds_kernel<16, 2><<<GB, 256, 0, stream>>>(buf, 512, WT3, bb3, d_out, 128, NN, 0, 1, mode);
}